// Round 1
// baseline (707.943 us; speedup 1.0000x reference)
//
#include <hip/hip_runtime.h>
#include <hip/hip_bf16.h>
#include <math.h>

// Problem constants
#define NTOK  4096      // B*T
#define CDIM  1024
#define HDIM  4096
#define NEXP  8
#define TOPK  2

using short8 = __attribute__((ext_vector_type(8))) short;
using f32x4  = __attribute__((ext_vector_type(4))) float;
using us4    = __attribute__((ext_vector_type(4))) unsigned short;

__device__ inline ushort f2bf(float f) {
    uint32_t u = __builtin_bit_cast(uint32_t, f);
    uint32_t r = (u + 0x7FFFu + ((u >> 16) & 1u)) >> 16;
    return (ushort)r;
}

// async global->LDS, 16 B per lane; LDS dest = wave-uniform base + lane*16
__device__ __forceinline__ void gl_lds16(const void* g, void* l) {
    __builtin_amdgcn_global_load_lds(
        (const __attribute__((address_space(1))) void*)(void*)g,
        (__attribute__((address_space(3))) void*)l, 16, 0, 0);
}

// ---------------------------------------------------------------------------
// Gate: one wave per token. fp32 logits, top-2, normalized weights.
// Also converts x to bf16.
__global__ __launch_bounds__(256)
void gate_kernel(const float* __restrict__ x, const float* __restrict__ Wg,
                 const float* __restrict__ bg, int* __restrict__ counts,
                 int* __restrict__ tlist, float* __restrict__ wslot,
                 ushort* __restrict__ xbf) {
    int wave = threadIdx.x >> 6, lane = threadIdx.x & 63;
    int t = blockIdx.x * 4 + wave;
    const float* xr = x + (size_t)t * CDIM;

    float acc[NEXP];
#pragma unroll
    for (int e = 0; e < NEXP; e++) acc[e] = 0.f;

#pragma unroll
    for (int i = 0; i < CDIM / 64; i++) {
        int c = lane + 64 * i;
        float xv = xr[c];
        xbf[(size_t)t * CDIM + c] = f2bf(xv);
        const float* wr = Wg + (size_t)c * NEXP;
#pragma unroll
        for (int e = 0; e < NEXP; e++) acc[e] += xv * wr[e];
    }
#pragma unroll
    for (int e = 0; e < NEXP; e++) {
        float v = acc[e];
        for (int off = 32; off > 0; off >>= 1) v += __shfl_xor(v, off);
        acc[e] = v + bg[e];
    }
    if (lane == 0) {
        int i1 = 0; float m1 = acc[0];
#pragma unroll
        for (int e = 1; e < NEXP; e++) if (acc[e] > m1) { m1 = acc[e]; i1 = e; }
        int i2 = -1; float m2 = -1e30f;
#pragma unroll
        for (int e = 0; e < NEXP; e++) if (e != i1 && acc[e] > m2) { m2 = acc[e]; i2 = e; }
        // softmax top-2 renormalized: w0 = g1/(g1+g2) = 1/(1+exp(l2-l1))
        float w0 = 1.f / (1.f + expf(m2 - m1));
        float w1 = 1.f - w0;
        int p0 = atomicAdd(&counts[i1], 1);
        tlist[i1 * NTOK + p0] = t * 2;
        int p1 = atomicAdd(&counts[i2], 1);
        tlist[i2 * NTOK + p1] = t * 2 + 1;
        wslot[t * 2]     = w0;
        wslot[t * 2 + 1] = w1;
    }
}

// ---------------------------------------------------------------------------
// Transpose + fp32->bf16: in [E][R][Ccols] f32 -> out [E][Ccols][R] bf16
// 64x64 tiles, 256 threads. float4 global loads, ushort4 (8B) global stores.
// LDS pitch 65 floats: row r, col c -> bank (r + c) & 31, so both the
// row-write (4tx+ty spread) and the column-read (4tx+ty spread) are <=2-way
// (free). Pitch 68 + vector stores was an 8-way conflict on the column read.
// grid (Ccols/64, R/64, E)
__global__ __launch_bounds__(256)
void transpose_kernel(const float* __restrict__ in, ushort* __restrict__ out,
                      int R, int Ccols) {
    __shared__ float tile[64][65];
    int e = blockIdx.z;
    const float* src = in + (size_t)e * R * Ccols;
    ushort* dst = out + (size_t)e * Ccols * R;
    int c0 = blockIdx.x * 64, r0 = blockIdx.y * 64;
    int tid = threadIdx.x;
    int tx = tid & 15, ty = tid >> 4;
#pragma unroll
    for (int j = 0; j < 4; j++) {
        int r = ty + 16 * j;
        float4 v = *(const float4*)&src[(size_t)(r0 + r) * Ccols + c0 + tx * 4];
        tile[r][tx * 4 + 0] = v.x;
        tile[r][tx * 4 + 1] = v.y;
        tile[r][tx * 4 + 2] = v.z;
        tile[r][tx * 4 + 3] = v.w;
    }
    __syncthreads();
#pragma unroll
    for (int j = 0; j < 4; j++) {
        int c = ty + 16 * j;
        us4 o;
#pragma unroll
        for (int i = 0; i < 4; i++) o[i] = f2bf(tile[tx * 4 + i][c]);
        *(us4*)&dst[(size_t)(c0 + c) * R + r0 + tx * 4] = o;
    }
}

// ---------------------------------------------------------------------------
// Sparse-expert GEMM: rows gathered by per-expert token list.
//   A  : bf16 [*, K], row index = tlist_value >> ashift
//   Bt : bf16 [E][N][K] (pre-transposed so rows are K-consecutive)
//   Out: row index = tlist_value; bf16 (h) or f32 (y)
// 128x128 tile, BK=32, 4 waves x (64x64), v_mfma_f32_16x16x32_bf16.
//
// Pipeline (T3 minimum 2-phase): double-buffered LDS, one barrier per K-step.
//   STAGE(next buf) is issued BEFORE compute(cur buf), so the global_load_lds
//   for step t+1 is in flight during step t's ds_read+MFMA; the compiler's
//   vmcnt(0) drain at the barrier then completes almost for free. The old
//   structure (stage -> barrier -> compute -> barrier) had zero overlap.
//
// LDS chunk swizzle (both-sides-or-neither, rule 21): rows are 64 B so the
// fragment ds_read_b128 was 8-way bank-conflicted (8.8M conflict cycles per
// dispatch). We pre-swizzle the GLOBAL source chunk q ^= ((row>>1)&3) while
// keeping the LDS destination linear (required by global_load_lds), and
// apply the same XOR on the read address -> 2-way (free).
template<int GELU, int OUTBF16>
__global__ __launch_bounds__(256, 3)
void moe_gemm(const ushort* __restrict__ A, const ushort* __restrict__ Bt,
              const float* __restrict__ bias, const int* __restrict__ tlist,
              const int* __restrict__ counts, void* __restrict__ Out,
              int K, int N, int ashift) {
    int e = blockIdx.z;
    int cnt = counts[e];
    int m0 = blockIdx.y * 128;
    if (m0 >= cnt) return;
    int n0 = blockIdx.x * 128;

    __shared__ ushort As[2][128 * 32];
    __shared__ ushort Bs[2][128 * 32];
    __shared__ int rowv[128];

    int tid = threadIdx.x;
    if (tid < 128) {
        int r = m0 + tid;
        rowv[tid] = tlist[e * NTOK + (r < cnt ? r : cnt - 1)];
    }
    __syncthreads();

    const ushort* Be = Bt + (size_t)e * N * K;

    int lane = tid & 63, w = tid >> 6;
    int wm = (w >> 1) * 64, wn = (w & 1) * 64;
    int quad = lane >> 4, l16 = lane & 15;

    // Staging: thread covers rows srow and srow+64, one 16 B chunk each.
    // Source chunk is pre-swizzled; LDS dest stays linear (base + lane*16).
    int srow   = tid >> 2;
    int schunk = (tid & 3) ^ ((tid >> 3) & 3);   // == q ^ ((srow>>1)&3)
    const ushort* pa0 = A  + (size_t)(rowv[srow]      >> ashift) * K + schunk * 8;
    const ushort* pa1 = A  + (size_t)(rowv[srow + 64] >> ashift) * K + schunk * 8;
    const ushort* pb0 = Be + (size_t)(n0 + srow)      * K + schunk * 8;
    const ushort* pb1 = Be + (size_t)(n0 + srow + 64) * K + schunk * 8;

    // Fragment-read swizzle: phys chunk = quad ^ ((row>>1)&3); the row's
    // high bits (wm/wn + mt*16) contribute 0 mod 4, so it's quad ^ ((l16>>1)&3).
    int swr  = quad ^ ((l16 >> 1) & 3);
    int aidx = (wm + l16) * 32 + swr * 8;
    int bidx = (wn + l16) * 32 + swr * 8;

    f32x4 acc[4][4] = {};

    auto STAGE = [&](int buf) {
        gl_lds16(pa0, &As[buf][(w * 16) * 32]);
        gl_lds16(pa1, &As[buf][(w * 16 + 64) * 32]);
        gl_lds16(pb0, &Bs[buf][(w * 16) * 32]);
        gl_lds16(pb1, &Bs[buf][(w * 16 + 64) * 32]);
        pa0 += 32; pa1 += 32; pb0 += 32; pb1 += 32;
    };
    auto COMPUTE = [&](int buf) {
        short8 a[4], b[4];
#pragma unroll
        for (int mt = 0; mt < 4; mt++) a[mt] = *(short8*)&As[buf][aidx + mt * 512];
#pragma unroll
        for (int nt = 0; nt < 4; nt++) b[nt] = *(short8*)&Bs[buf][bidx + nt * 512];
#pragma unroll
        for (int mt = 0; mt < 4; mt++)
#pragma unroll
            for (int nt = 0; nt < 4; nt++)
                acc[mt][nt] = __builtin_amdgcn_mfma_f32_16x16x32_bf16(
                    a[mt], b[nt], acc[mt][nt], 0, 0, 0);
    };

    int nsteps = K >> 5;          // 32 (GEMM1) or 128 (GEMM2) -- even
    STAGE(0);
    __syncthreads();              // drains vmcnt(0): buf0 ready
    for (int i = 0; i < nsteps - 2; i += 2) {
        STAGE(1);                 // step i+1 in flight under compute(i)
        COMPUTE(0);
        __syncthreads();
        STAGE(0);                 // step i+2 in flight under compute(i+1)
        COMPUTE(1);
        __syncthreads();
    }
    STAGE(1);                     // final step nsteps-1
    COMPUTE(0);                   // step nsteps-2
    __syncthreads();
    COMPUTE(1);                   // step nsteps-1

    // Epilogue. C/D layout: col = lane&15, row = (lane>>4)*4 + reg.
    float* outF = (float*)Out;
    ushort* outH = (ushort*)Out;
    const float* be = bias + (size_t)e * N;
#pragma unroll
    for (int mt = 0; mt < 4; mt++) {
#pragma unroll
        for (int r = 0; r < 4; r++) {
            int lrow = wm + mt * 16 + quad * 4 + r;
            if (m0 + lrow < cnt) {
                int v = rowv[lrow];
                size_t base = (size_t)v * N;
#pragma unroll
                for (int nt = 0; nt < 4; nt++) {
                    int col = n0 + wn + nt * 16 + l16;
                    float val = acc[mt][nt][r] + be[col];
                    if (GELU) val = 0.5f * val * (1.0f + erff(val * 0.70710678118654752f));
                    if (OUTBF16) outH[base + col] = f2bf(val);
                    else         outF[base + col] = val;
                }
            }
        }
    }
}

// ---------------------------------------------------------------------------
// out[t] = w0 * y[2t] + w1 * y[2t+1]   (fully coalesced, writes every element)
__global__ __launch_bounds__(256)
void combine_kernel(const float* __restrict__ y, const float* __restrict__ wslot,
                    float* __restrict__ out) {
    int idx = blockIdx.x * 256 + threadIdx.x;     // one float4 each
    int c4 = idx & (CDIM / 4 - 1);
    int t = idx >> 8;                              // CDIM/4 == 256
    float w0 = wslot[2 * t], w1 = wslot[2 * t + 1];
    const float4* y0 = (const float4*)(y + (size_t)(2 * t) * CDIM);
    const float4* y1 = (const float4*)(y + (size_t)(2 * t + 1) * CDIM);
    float4 a = y0[c4], b = y1[c4], o;
    o.x = w0 * a.x + w1 * b.x;
    o.y = w0 * a.y + w1 * b.y;
    o.z = w0 * a.z + w1 * b.z;
    o.w = w0 * a.w + w1 * b.w;
    ((float4*)(out + (size_t)t * CDIM))[c4] = o;
}

// ---------------------------------------------------------------------------
extern "C" void kernel_launch(void* const* d_in, const int* in_sizes, int n_in,
                              void* d_out, int out_size, void* d_ws, size_t ws_size,
                              hipStream_t stream) {
    const float* x  = (const float*)d_in[0];
    const float* Wg = (const float*)d_in[1];
    const float* bg = (const float*)d_in[2];
    const float* W1 = (const float*)d_in[3];
    const float* b1 = (const float*)d_in[4];
    const float* W2 = (const float*)d_in[5];
    const float* b2 = (const float*)d_in[6];
    float* out = (float*)d_out;
    char* ws = (char*)d_ws;

    // workspace layout (bytes)
    size_t off = 0;
    int*    counts = (int*)(ws + off);    off += 256;
    int*    tlist  = (int*)(ws + off);    off += (size_t)NEXP * NTOK * 4;        // 128 KB
    float*  wslot  = (float*)(ws + off);  off += (size_t)NTOK * TOPK * 4;        // 32 KB
    ushort* xbf    = (ushort*)(ws + off); off += (size_t)NTOK * CDIM * 2;        // 8 MB
    ushort* WT     = (ushort*)(ws + off); off += (size_t)NEXP * CDIM * HDIM * 2; // 64 MB (shared W1T/W2T)
    ushort* h      = (ushort*)(ws + off); off += (size_t)NTOK * TOPK * HDIM * 2; // 64 MB
    float*  y      = (float*)(ws + off);  off += (size_t)NTOK * TOPK * CDIM * 4; // 32 MB

    hipMemsetAsync(counts, 0, NEXP * sizeof(int), stream);

    gate_kernel<<<NTOK / 4, 256, 0, stream>>>(x, Wg, bg, counts, tlist, wslot, xbf);

    // W1 [E][C][H] -> WT [E][H][C] bf16
    transpose_kernel<<<dim3(HDIM / 64, CDIM / 64, NEXP), 256, 0, stream>>>(
        W1, WT, CDIM, HDIM);

    // h[slot] = gelu(x @ W1 + b1), bf16
    moe_gemm<1, 1><<<dim3(HDIM / 128, NTOK / 128, NEXP), 256, 0, stream>>>(
        xbf, WT, b1, tlist, counts, (void*)h, CDIM, HDIM, 1);

    // W2 [E][H][C] -> WT [E][C][H] bf16  (reuses WT buffer; stream-ordered
    // after GEMM1 so the overwrite is safe)
    transpose_kernel<<<dim3(CDIM / 64, HDIM / 64, NEXP), 256, 0, stream>>>(
        W2, WT, HDIM, CDIM);

    // y[slot] = h @ W2 + b2, f32
    moe_gemm<0, 0><<<dim3(CDIM / 128, NTOK / 128, NEXP), 256, 0, stream>>>(
        h, WT, b2, tlist, counts, (void*)y, HDIM, CDIM, 0);

    combine_kernel<<<(NTOK * CDIM / 4) / 256, 256, 0, stream>>>(y, wslot, out);
}

// Round 2
// 702.673 us; speedup vs baseline: 1.0075x; 1.0075x over previous
//
#include <hip/hip_runtime.h>
#include <hip/hip_bf16.h>
#include <math.h>

// Problem constants
#define NTOK  4096      // B*T
#define CDIM  1024
#define HDIM  4096
#define NEXP  8
#define TOPK  2

using short8 = __attribute__((ext_vector_type(8))) short;
using f32x4  = __attribute__((ext_vector_type(4))) float;
using us4    = __attribute__((ext_vector_type(4))) unsigned short;

__device__ inline ushort f2bf(float f) {
    uint32_t u = __builtin_bit_cast(uint32_t, f);
    uint32_t r = (u + 0x7FFFu + ((u >> 16) & 1u)) >> 16;
    return (ushort)r;
}

// async global->LDS, 16 B per lane; LDS dest = wave-uniform base + lane*16
__device__ __forceinline__ void gl_lds16(const void* g, void* l) {
    __builtin_amdgcn_global_load_lds(
        (const __attribute__((address_space(1))) void*)(void*)g,
        (__attribute__((address_space(3))) void*)l, 16, 0, 0);
}

// ---------------------------------------------------------------------------
// Gate: one wave per token. fp32 logits, top-2, normalized weights.
// Also converts x to bf16.
__global__ __launch_bounds__(256)
void gate_kernel(const float* __restrict__ x, const float* __restrict__ Wg,
                 const float* __restrict__ bg, int* __restrict__ counts,
                 int* __restrict__ tlist, float* __restrict__ wslot,
                 ushort* __restrict__ xbf) {
    int wave = threadIdx.x >> 6, lane = threadIdx.x & 63;
    int t = blockIdx.x * 4 + wave;
    const float* xr = x + (size_t)t * CDIM;

    float acc[NEXP];
#pragma unroll
    for (int e = 0; e < NEXP; e++) acc[e] = 0.f;

#pragma unroll
    for (int i = 0; i < CDIM / 64; i++) {
        int c = lane + 64 * i;
        float xv = xr[c];
        xbf[(size_t)t * CDIM + c] = f2bf(xv);
        const float* wr = Wg + (size_t)c * NEXP;
#pragma unroll
        for (int e = 0; e < NEXP; e++) acc[e] += xv * wr[e];
    }
#pragma unroll
    for (int e = 0; e < NEXP; e++) {
        float v = acc[e];
        for (int off = 32; off > 0; off >>= 1) v += __shfl_xor(v, off);
        acc[e] = v + bg[e];
    }
    if (lane == 0) {
        int i1 = 0; float m1 = acc[0];
#pragma unroll
        for (int e = 1; e < NEXP; e++) if (acc[e] > m1) { m1 = acc[e]; i1 = e; }
        int i2 = -1; float m2 = -1e30f;
#pragma unroll
        for (int e = 0; e < NEXP; e++) if (e != i1 && acc[e] > m2) { m2 = acc[e]; i2 = e; }
        // softmax top-2 renormalized: w0 = g1/(g1+g2) = 1/(1+exp(l2-l1))
        float w0 = 1.f / (1.f + expf(m2 - m1));
        float w1 = 1.f - w0;
        int p0 = atomicAdd(&counts[i1], 1);
        tlist[i1 * NTOK + p0] = t * 2;
        int p1 = atomicAdd(&counts[i2], 1);
        tlist[i2 * NTOK + p1] = t * 2 + 1;
        wslot[t * 2]     = w0;
        wslot[t * 2 + 1] = w1;
    }
}

// ---------------------------------------------------------------------------
// Transpose + fp32->bf16: in [E][R][Ccols] f32 -> out [E][Ccols][R] bf16
// 64x64 tiles, 256 threads. float4 global loads, ushort4 (8B) global stores.
// LDS pitch 65 floats: row r, col c -> bank (r + c) & 31, so both the
// row-write (4tx+ty spread) and the column-read (4tx+ty spread) are <=2-way
// (free).
// grid (Ccols/64, R/64, E)
__global__ __launch_bounds__(256)
void transpose_kernel(const float* __restrict__ in, ushort* __restrict__ out,
                      int R, int Ccols) {
    __shared__ float tile[64][65];
    int e = blockIdx.z;
    const float* src = in + (size_t)e * R * Ccols;
    ushort* dst = out + (size_t)e * Ccols * R;
    int c0 = blockIdx.x * 64, r0 = blockIdx.y * 64;
    int tid = threadIdx.x;
    int tx = tid & 15, ty = tid >> 4;
#pragma unroll
    for (int j = 0; j < 4; j++) {
        int r = ty + 16 * j;
        float4 v = *(const float4*)&src[(size_t)(r0 + r) * Ccols + c0 + tx * 4];
        tile[r][tx * 4 + 0] = v.x;
        tile[r][tx * 4 + 1] = v.y;
        tile[r][tx * 4 + 2] = v.z;
        tile[r][tx * 4 + 3] = v.w;
    }
    __syncthreads();
#pragma unroll
    for (int j = 0; j < 4; j++) {
        int c = ty + 16 * j;
        us4 o;
#pragma unroll
        for (int i = 0; i < 4; i++) o[i] = f2bf(tile[tx * 4 + i][c]);
        *(us4*)&dst[(size_t)(c0 + c) * R + r0 + tx * 4] = o;
    }
}

// ---------------------------------------------------------------------------
// Sparse-expert GEMM: rows gathered by per-expert token list.
//   A  : bf16 [*, K], row index = tlist_value >> ashift
//   Bt : bf16 [E][N][K] (pre-transposed so rows are K-consecutive)
//   Out: row index = tlist_value; bf16 (h) or f32 (y)
// 128x128 tile, BK=32, 4 waves x (64x64), v_mfma_f32_16x16x32_bf16.
//
// Split-K (GEMM2 only): blockIdx.x packs (xtile, split); each split computes
// ksplit of K and writes a SEPARATE partial buffer (Out + split*psz) --
// deterministic, no atomics. Bias added by split 0 only; combine sums the
// partials. Rationale: GEMM2 has only 512 live blocks (2/CU, occupancy 18%),
// latency-bound at the per-step barrier drain; x2 split -> 4 blocks/CU (the
// 33 KB LDS cap), doubling the co-resident compute that covers the drain.
//
// Pipeline (T3 minimum 2-phase): double-buffered LDS, one barrier per K-step.
// LDS chunk swizzle (both-sides-or-neither, rule 21): global source chunk
// pre-swizzled q ^= ((row>>1)&3), LDS dest linear, same XOR on ds_read.
template<int GELU, int OUTBF16>
__global__ __launch_bounds__(256, 3)
void moe_gemm(const ushort* __restrict__ A, const ushort* __restrict__ Bt,
              const float* __restrict__ bias, const int* __restrict__ tlist,
              const int* __restrict__ counts, void* __restrict__ Out,
              int K, int N, int ashift, int nxmask, int nxshift, int ksplit,
              size_t psz) {
    int e = blockIdx.z;
    int cnt = counts[e];
    int m0 = blockIdx.y * 128;
    if (m0 >= cnt) return;
    int n0 = (blockIdx.x & nxmask) * 128;
    int split = blockIdx.x >> nxshift;
    int kbeg = split * ksplit;

    __shared__ ushort As[2][128 * 32];
    __shared__ ushort Bs[2][128 * 32];
    __shared__ int rowv[128];

    int tid = threadIdx.x;
    if (tid < 128) {
        int r = m0 + tid;
        rowv[tid] = tlist[e * NTOK + (r < cnt ? r : cnt - 1)];
    }
    __syncthreads();

    const ushort* Be = Bt + (size_t)e * N * K;

    int lane = tid & 63, w = tid >> 6;
    int wm = (w >> 1) * 64, wn = (w & 1) * 64;
    int quad = lane >> 4, l16 = lane & 15;

    // Staging: thread covers rows srow and srow+64, one 16 B chunk each.
    // Source chunk is pre-swizzled; LDS dest stays linear (base + lane*16).
    int srow   = tid >> 2;
    int schunk = (tid & 3) ^ ((tid >> 3) & 3);   // == q ^ ((srow>>1)&3)
    const ushort* pa0 = A  + (size_t)(rowv[srow]      >> ashift) * K + kbeg + schunk * 8;
    const ushort* pa1 = A  + (size_t)(rowv[srow + 64] >> ashift) * K + kbeg + schunk * 8;
    const ushort* pb0 = Be + (size_t)(n0 + srow)      * K + kbeg + schunk * 8;
    const ushort* pb1 = Be + (size_t)(n0 + srow + 64) * K + kbeg + schunk * 8;

    // Fragment-read swizzle: phys chunk = quad ^ ((row>>1)&3); the row's
    // high bits (wm/wn + mt*16) contribute 0 mod 4, so it's quad ^ ((l16>>1)&3).
    int swr  = quad ^ ((l16 >> 1) & 3);
    int aidx = (wm + l16) * 32 + swr * 8;
    int bidx = (wn + l16) * 32 + swr * 8;

    f32x4 acc[4][4] = {};

    auto STAGE = [&](int buf) {
        gl_lds16(pa0, &As[buf][(w * 16) * 32]);
        gl_lds16(pa1, &As[buf][(w * 16 + 64) * 32]);
        gl_lds16(pb0, &Bs[buf][(w * 16) * 32]);
        gl_lds16(pb1, &Bs[buf][(w * 16 + 64) * 32]);
        pa0 += 32; pa1 += 32; pb0 += 32; pb1 += 32;
    };
    auto COMPUTE = [&](int buf) {
        short8 a[4], b[4];
#pragma unroll
        for (int mt = 0; mt < 4; mt++) a[mt] = *(short8*)&As[buf][aidx + mt * 512];
#pragma unroll
        for (int nt = 0; nt < 4; nt++) b[nt] = *(short8*)&Bs[buf][bidx + nt * 512];
#pragma unroll
        for (int mt = 0; mt < 4; mt++)
#pragma unroll
            for (int nt = 0; nt < 4; nt++)
                acc[mt][nt] = __builtin_amdgcn_mfma_f32_16x16x32_bf16(
                    a[mt], b[nt], acc[mt][nt], 0, 0, 0);
    };

    int nsteps = ksplit >> 5;     // 32 (GEMM1) or 64 (GEMM2 split) -- even
    STAGE(0);
    __syncthreads();              // drains vmcnt(0): buf0 ready
    for (int i = 0; i < nsteps - 2; i += 2) {
        STAGE(1);                 // step i+1 in flight under compute(i)
        COMPUTE(0);
        __syncthreads();
        STAGE(0);                 // step i+2 in flight under compute(i+1)
        COMPUTE(1);
        __syncthreads();
    }
    STAGE(1);                     // final step nsteps-1
    COMPUTE(0);                   // step nsteps-2
    __syncthreads();
    COMPUTE(1);                   // step nsteps-1

    // Epilogue. C/D layout: col = lane&15, row = (lane>>4)*4 + reg.
    float* outF = (float*)Out + split * psz;
    ushort* outH = (ushort*)Out;
    const float* be = bias + (size_t)e * N;
#pragma unroll
    for (int mt = 0; mt < 4; mt++) {
#pragma unroll
        for (int r = 0; r < 4; r++) {
            int lrow = wm + mt * 16 + quad * 4 + r;
            if (m0 + lrow < cnt) {
                int v = rowv[lrow];
                size_t base = (size_t)v * N;
#pragma unroll
                for (int nt = 0; nt < 4; nt++) {
                    int col = n0 + wn + nt * 16 + l16;
                    float val = acc[mt][nt][r] + (split == 0 ? be[col] : 0.f);
                    if (GELU) val = 0.5f * val * (1.0f + erff(val * 0.70710678118654752f));
                    if (OUTBF16) outH[base + col] = f2bf(val);
                    else         outF[base + col] = val;
                }
            }
        }
    }
}

// ---------------------------------------------------------------------------
// out[t] = w0 * (ya[2t]+yb[2t]) + w1 * (ya[2t+1]+yb[2t+1])
// (split-K partial sum folded in; fully coalesced)
__global__ __launch_bounds__(256)
void combine_kernel(const float* __restrict__ y, const float* __restrict__ wslot,
                    float* __restrict__ out) {
    const float* y2 = y + (size_t)NTOK * TOPK * CDIM;   // split-1 partials
    int idx = blockIdx.x * 256 + threadIdx.x;     // one float4 each
    int c4 = idx & (CDIM / 4 - 1);
    int t = idx >> 8;                              // CDIM/4 == 256
    float w0 = wslot[2 * t], w1 = wslot[2 * t + 1];
    const float4* y0a = (const float4*)(y  + (size_t)(2 * t) * CDIM);
    const float4* y1a = (const float4*)(y  + (size_t)(2 * t + 1) * CDIM);
    const float4* y0b = (const float4*)(y2 + (size_t)(2 * t) * CDIM);
    const float4* y1b = (const float4*)(y2 + (size_t)(2 * t + 1) * CDIM);
    float4 a0 = y0a[c4], a1 = y0b[c4], b0 = y1a[c4], b1 = y1b[c4], o;
    o.x = w0 * (a0.x + a1.x) + w1 * (b0.x + b1.x);
    o.y = w0 * (a0.y + a1.y) + w1 * (b0.y + b1.y);
    o.z = w0 * (a0.z + a1.z) + w1 * (b0.z + b1.z);
    o.w = w0 * (a0.w + a1.w) + w1 * (b0.w + b1.w);
    ((float4*)(out + (size_t)t * CDIM))[c4] = o;
}

// ---------------------------------------------------------------------------
extern "C" void kernel_launch(void* const* d_in, const int* in_sizes, int n_in,
                              void* d_out, int out_size, void* d_ws, size_t ws_size,
                              hipStream_t stream) {
    const float* x  = (const float*)d_in[0];
    const float* Wg = (const float*)d_in[1];
    const float* bg = (const float*)d_in[2];
    const float* W1 = (const float*)d_in[3];
    const float* b1 = (const float*)d_in[4];
    const float* W2 = (const float*)d_in[5];
    const float* b2 = (const float*)d_in[6];
    float* out = (float*)d_out;
    char* ws = (char*)d_ws;

    // workspace layout (bytes)
    size_t off = 0;
    int*    counts = (int*)(ws + off);    off += 256;
    int*    tlist  = (int*)(ws + off);    off += (size_t)NEXP * NTOK * 4;        // 128 KB
    float*  wslot  = (float*)(ws + off);  off += (size_t)NTOK * TOPK * 4;        // 32 KB
    ushort* xbf    = (ushort*)(ws + off); off += (size_t)NTOK * CDIM * 2;        // 8 MB
    ushort* WT     = (ushort*)(ws + off); off += (size_t)NEXP * CDIM * HDIM * 2; // 64 MB (shared W1T/W2T)
    ushort* h      = (ushort*)(ws + off); off += (size_t)NTOK * TOPK * HDIM * 2; // 64 MB
    float*  y      = (float*)(ws + off);  off += (size_t)NTOK * TOPK * CDIM * 4 * 2; // 64 MB (2 split-K partials)

    hipMemsetAsync(counts, 0, NEXP * sizeof(int), stream);

    gate_kernel<<<NTOK / 4, 256, 0, stream>>>(x, Wg, bg, counts, tlist, wslot, xbf);

    // W1 [E][C][H] -> WT [E][H][C] bf16
    transpose_kernel<<<dim3(HDIM / 64, CDIM / 64, NEXP), 256, 0, stream>>>(
        W1, WT, CDIM, HDIM);

    // h[slot] = gelu(x @ W1 + b1), bf16.  No split (grid already 8 blocks/CU).
    moe_gemm<1, 1><<<dim3(HDIM / 128, NTOK / 128, NEXP), 256, 0, stream>>>(
        xbf, WT, b1, tlist, counts, (void*)h, CDIM, HDIM, 1,
        HDIM / 128 - 1, 5, CDIM, 0);

    // W2 [E][H][C] -> WT [E][C][H] bf16  (reuses WT buffer; stream-ordered
    // after GEMM1 so the overwrite is safe)
    transpose_kernel<<<dim3(CDIM / 64, HDIM / 64, NEXP), 256, 0, stream>>>(
        W2, WT, HDIM, CDIM);

    // y[split][slot] = h @ W2 (+ b2 on split 0), f32; split-K x2.
    moe_gemm<0, 0><<<dim3((CDIM / 128) * 2, NTOK / 128, NEXP), 256, 0, stream>>>(
        h, WT, b2, tlist, counts, (void*)y, HDIM, CDIM, 0,
        CDIM / 128 - 1, 3, HDIM / 2, (size_t)NTOK * TOPK * CDIM);

    combine_kernel<<<(NTOK * CDIM / 4) / 256, 256, 0, stream>>>(y, wslot, out);
}

// Round 3
// 687.424 us; speedup vs baseline: 1.0298x; 1.0222x over previous
//
#include <hip/hip_runtime.h>
#include <hip/hip_bf16.h>
#include <math.h>

// Problem constants
#define NTOK  4096      // B*T
#define CDIM  1024
#define HDIM  4096
#define NEXP  8
#define TOPK  2

using short8 = __attribute__((ext_vector_type(8))) short;
using f32x4  = __attribute__((ext_vector_type(4))) float;

__device__ inline ushort f2bf(float f) {
    uint32_t u = __builtin_bit_cast(uint32_t, f);
    uint32_t r = (u + 0x7FFFu + ((u >> 16) & 1u)) >> 16;
    return (ushort)r;
}

// async global->LDS, 16 B per lane; LDS dest = wave-uniform base + lane*16
__device__ __forceinline__ void gl_lds16(const void* g, void* l) {
    __builtin_amdgcn_global_load_lds(
        (const __attribute__((address_space(1))) void*)(void*)g,
        (__attribute__((address_space(3))) void*)l, 16, 0, 0);
}

// ---------------------------------------------------------------------------
// Gate: one wave per token. fp32 logits, top-2, normalized weights.
// Also converts x to bf16.
__global__ __launch_bounds__(256)
void gate_kernel(const float* __restrict__ x, const float* __restrict__ Wg,
                 const float* __restrict__ bg, int* __restrict__ counts,
                 int* __restrict__ tlist, float* __restrict__ wslot,
                 ushort* __restrict__ xbf) {
    int wave = threadIdx.x >> 6, lane = threadIdx.x & 63;
    int t = blockIdx.x * 4 + wave;
    const float* xr = x + (size_t)t * CDIM;

    float acc[NEXP];
#pragma unroll
    for (int e = 0; e < NEXP; e++) acc[e] = 0.f;

#pragma unroll
    for (int i = 0; i < CDIM / 64; i++) {
        int c = lane + 64 * i;
        float xv = xr[c];
        xbf[(size_t)t * CDIM + c] = f2bf(xv);
        const float* wr = Wg + (size_t)c * NEXP;
#pragma unroll
        for (int e = 0; e < NEXP; e++) acc[e] += xv * wr[e];
    }
#pragma unroll
    for (int e = 0; e < NEXP; e++) {
        float v = acc[e];
        for (int off = 32; off > 0; off >>= 1) v += __shfl_xor(v, off);
        acc[e] = v + bg[e];
    }
    if (lane == 0) {
        int i1 = 0; float m1 = acc[0];
#pragma unroll
        for (int e = 1; e < NEXP; e++) if (acc[e] > m1) { m1 = acc[e]; i1 = e; }
        int i2 = -1; float m2 = -1e30f;
#pragma unroll
        for (int e = 0; e < NEXP; e++) if (e != i1 && acc[e] > m2) { m2 = acc[e]; i2 = e; }
        // softmax top-2 renormalized: w0 = g1/(g1+g2) = 1/(1+exp(l2-l1))
        float w0 = 1.f / (1.f + expf(m2 - m1));
        float w1 = 1.f - w0;
        int p0 = atomicAdd(&counts[i1], 1);
        tlist[i1 * NTOK + p0] = t * 2;
        int p1 = atomicAdd(&counts[i2], 1);
        tlist[i2 * NTOK + p1] = t * 2 + 1;
        wslot[t * 2]     = w0;
        wslot[t * 2 + 1] = w1;
    }
}

// ---------------------------------------------------------------------------
// Transpose + fp32->bf16: in [E][R][Ccols] f32 -> out [E][Ccols][R] bf16
// 64x64 tiles, 256 threads.
//
// Rebuilt for vector LDS ops at the bank floor (old version: 16 ds_write_b32
// + 64 ds_read_b32 per thread, 8 B stores -> issue-bound at ~1.3 TB/s):
//   read : float4 x4 (rows 4ty..4ty+3, cols 4tx..4tx+3), 1 KB/wave-instr
//   LDS  : bf16 tile [c][r], PO2 pitch 128 B, 16 B granules XOR-swizzled by
//          (c>>2)&7 -> both write (b64) and read (b128) sit at the N-way
//          floor (no extra bank serialization)
//   write: in-register 4x4 transpose -> ds_write_b64 (4 bf16 = rows r..r+3)
//   store: ds_read_b128 -> 16 B global stores, 8 lanes cover one full
//          64-elem dst row -> 1 KB/wave-instr fully contiguous
// grid (Ccols/64, R/64, E)
__global__ __launch_bounds__(256)
void transpose_kernel(const float* __restrict__ in, ushort* __restrict__ out,
                      int R, int Ccols) {
    __shared__ ushort tile[64 * 64];   // 8 KB, swizzled addressing below
    int e = blockIdx.z;
    const float* src = in + (size_t)e * R * Ccols;
    ushort* dst = out + (size_t)e * Ccols * R;
    int c0 = blockIdx.x * 64, r0 = blockIdx.y * 64;
    int tid = threadIdx.x;
    int tx = tid & 15, ty = tid >> 4;

    float4 v[4];
#pragma unroll
    for (int j = 0; j < 4; j++)
        v[j] = *(const float4*)&src[(size_t)(r0 + ty * 4 + j) * Ccols + c0 + tx * 4];

    // element (c, r) lives at byte  c*128 + (((r>>3) ^ ((c>>2)&7))<<4) + (r&7)*2
#pragma unroll
    for (int i = 0; i < 4; i++) {
        int c = tx * 4 + i;
        uint2 pr;
        pr.x = (uint)f2bf(v[0][i]) | ((uint)f2bf(v[1][i]) << 16);
        pr.y = (uint)f2bf(v[2][i]) | ((uint)f2bf(v[3][i]) << 16);
        int gr = (ty >> 1) ^ ((c >> 2) & 7);            // r = 4*ty -> r>>3 = ty>>1
        int off = c * 128 + (gr << 4) + (ty & 1) * 8;   // bytes; 8-aligned
        *(uint2*)((char*)tile + off) = pr;
    }
    __syncthreads();

#pragma unroll
    for (int p = 0; p < 2; p++) {
        int c   = (tid >> 3) + 32 * p;                  // dst row within tile
        int rch = tid & 7;                              // r granule (8 elems)
        int gr  = rch ^ ((c >> 2) & 7);
        short8 val = *(short8*)((char*)tile + c * 128 + (gr << 4));
        *(short8*)&dst[(size_t)(c0 + c) * R + r0 + rch * 8] = val;
    }
}

// ---------------------------------------------------------------------------
// Sparse-expert GEMM: rows gathered by per-expert token list.
//   A  : bf16 [*, K], row index = tlist_value >> ashift
//   Bt : bf16 [E][N][K] (pre-transposed so rows are K-consecutive)
//   Out: row index = tlist_value; bf16 (h) or f32 (y)
// 128x128 tile, BK=32, 4 waves x (64x64), v_mfma_f32_16x16x32_bf16.
//
// 1-D grid, expert->XCD partition: flat = e + 8*(mt + 32*nj). Default XCD
// assignment round-robins the flat workgroup id over 8 XCDs, so expert e's
// blocks all land on XCD e: per-XCD L2 working set drops from ~50 MB (all
// experts mixed) to the one expert's A+B panels (10-17 MB), m-tiles
// innermost so co-resident blocks share B-tiles. Decode is bijective ->
// correctness never depends on the mapping (G16).
//
// Split-K (GEMM2 only): nj packs (n-tile, split); each split writes a
// SEPARATE partial buffer (Out + split*psz) -- deterministic, no atomics.
// Bias added by split 0 only; combine sums the partials.
//
// Pipeline (T3 minimum 2-phase): double-buffered LDS, one barrier per K-step,
// STAGE(next) issued before COMPUTE(cur) so loads fly under the MFMAs.
// LDS chunk swizzle (both-sides-or-neither, rule 21): global source chunk
// pre-swizzled q ^= ((row>>1)&3), LDS dest linear, same XOR on ds_read.
template<int GELU, int OUTBF16>
__global__ __launch_bounds__(256, 3)
void moe_gemm(const ushort* __restrict__ A, const ushort* __restrict__ Bt,
              const float* __restrict__ bias, const int* __restrict__ tlist,
              const int* __restrict__ counts, void* __restrict__ Out,
              int K, int N, int ashift, int nxmask, int nxshift, int ksplit,
              size_t psz) {
    int flat = blockIdx.x;
    int e  = flat & 7;
    int j  = flat >> 3;
    int mt = j & 31;              // m-tile innermost within an XCD
    int nj = j >> 5;
    int cnt = counts[e];
    int m0 = mt * 128;
    if (m0 >= cnt) return;
    int n0 = (nj & nxmask) * 128;
    int split = nj >> nxshift;
    int kbeg = split * ksplit;

    __shared__ ushort As[2][128 * 32];
    __shared__ ushort Bs[2][128 * 32];
    __shared__ int rowv[128];

    int tid = threadIdx.x;
    if (tid < 128) {
        int r = m0 + tid;
        rowv[tid] = tlist[e * NTOK + (r < cnt ? r : cnt - 1)];
    }
    __syncthreads();

    const ushort* Be = Bt + (size_t)e * N * K;

    int lane = tid & 63, w = tid >> 6;
    int wm = (w >> 1) * 64, wn = (w & 1) * 64;
    int quad = lane >> 4, l16 = lane & 15;

    // Staging: thread covers rows srow and srow+64, one 16 B chunk each.
    // Source chunk is pre-swizzled; LDS dest stays linear (base + lane*16).
    int srow   = tid >> 2;
    int schunk = (tid & 3) ^ ((tid >> 3) & 3);   // == q ^ ((srow>>1)&3)
    const ushort* pa0 = A  + (size_t)(rowv[srow]      >> ashift) * K + kbeg + schunk * 8;
    const ushort* pa1 = A  + (size_t)(rowv[srow + 64] >> ashift) * K + kbeg + schunk * 8;
    const ushort* pb0 = Be + (size_t)(n0 + srow)      * K + kbeg + schunk * 8;
    const ushort* pb1 = Be + (size_t)(n0 + srow + 64) * K + kbeg + schunk * 8;

    // Fragment-read swizzle: phys chunk = quad ^ ((row>>1)&3); the row's
    // high bits (wm/wn + mt*16) contribute 0 mod 4, so it's quad ^ ((l16>>1)&3).
    int swr  = quad ^ ((l16 >> 1) & 3);
    int aidx = (wm + l16) * 32 + swr * 8;
    int bidx = (wn + l16) * 32 + swr * 8;

    f32x4 acc[4][4] = {};

    auto STAGE = [&](int buf) {
        gl_lds16(pa0, &As[buf][(w * 16) * 32]);
        gl_lds16(pa1, &As[buf][(w * 16 + 64) * 32]);
        gl_lds16(pb0, &Bs[buf][(w * 16) * 32]);
        gl_lds16(pb1, &Bs[buf][(w * 16 + 64) * 32]);
        pa0 += 32; pa1 += 32; pb0 += 32; pb1 += 32;
    };
    auto COMPUTE = [&](int buf) {
        short8 a[4], b[4];
#pragma unroll
        for (int mti = 0; mti < 4; mti++) a[mti] = *(short8*)&As[buf][aidx + mti * 512];
#pragma unroll
        for (int nti = 0; nti < 4; nti++) b[nti] = *(short8*)&Bs[buf][bidx + nti * 512];
#pragma unroll
        for (int mti = 0; mti < 4; mti++)
#pragma unroll
            for (int nti = 0; nti < 4; nti++)
                acc[mti][nti] = __builtin_amdgcn_mfma_f32_16x16x32_bf16(
                    a[mti], b[nti], acc[mti][nti], 0, 0, 0);
    };

    int nsteps = ksplit >> 5;     // 32 (GEMM1) or 64 (GEMM2 split) -- even
    STAGE(0);
    __syncthreads();              // drains vmcnt(0): buf0 ready
    for (int i = 0; i < nsteps - 2; i += 2) {
        STAGE(1);                 // step i+1 in flight under compute(i)
        COMPUTE(0);
        __syncthreads();
        STAGE(0);                 // step i+2 in flight under compute(i+1)
        COMPUTE(1);
        __syncthreads();
    }
    STAGE(1);                     // final step nsteps-1
    COMPUTE(0);                   // step nsteps-2
    __syncthreads();
    COMPUTE(1);                   // step nsteps-1

    // Epilogue. C/D layout: col = lane&15, row = (lane>>4)*4 + reg.
    float* outF = (float*)Out + split * psz;
    ushort* outH = (ushort*)Out;
    const float* be = bias + (size_t)e * N;
#pragma unroll
    for (int mti = 0; mti < 4; mti++) {
#pragma unroll
        for (int r = 0; r < 4; r++) {
            int lrow = wm + mti * 16 + quad * 4 + r;
            if (m0 + lrow < cnt) {
                int v = rowv[lrow];
                size_t base = (size_t)v * N;
#pragma unroll
                for (int nti = 0; nti < 4; nti++) {
                    int col = n0 + wn + nti * 16 + l16;
                    float val = acc[mti][nti][r] + (split == 0 ? be[col] : 0.f);
                    if (GELU) val = 0.5f * val * (1.0f + erff(val * 0.70710678118654752f));
                    if (OUTBF16) outH[base + col] = f2bf(val);
                    else         outF[base + col] = val;
                }
            }
        }
    }
}

// ---------------------------------------------------------------------------
// out[t] = w0 * (ya[2t]+yb[2t]) + w1 * (ya[2t+1]+yb[2t+1])
// (split-K partial sum folded in; fully coalesced)
__global__ __launch_bounds__(256)
void combine_kernel(const float* __restrict__ y, const float* __restrict__ wslot,
                    float* __restrict__ out) {
    const float* y2 = y + (size_t)NTOK * TOPK * CDIM;   // split-1 partials
    int idx = blockIdx.x * 256 + threadIdx.x;     // one float4 each
    int c4 = idx & (CDIM / 4 - 1);
    int t = idx >> 8;                              // CDIM/4 == 256
    float w0 = wslot[2 * t], w1 = wslot[2 * t + 1];
    const float4* y0a = (const float4*)(y  + (size_t)(2 * t) * CDIM);
    const float4* y1a = (const float4*)(y  + (size_t)(2 * t + 1) * CDIM);
    const float4* y0b = (const float4*)(y2 + (size_t)(2 * t) * CDIM);
    const float4* y1b = (const float4*)(y2 + (size_t)(2 * t + 1) * CDIM);
    float4 a0 = y0a[c4], a1 = y0b[c4], b0 = y1a[c4], b1 = y1b[c4], o;
    o.x = w0 * (a0.x + a1.x) + w1 * (b0.x + b1.x);
    o.y = w0 * (a0.y + a1.y) + w1 * (b0.y + b1.y);
    o.z = w0 * (a0.z + a1.z) + w1 * (b0.z + b1.z);
    o.w = w0 * (a0.w + a1.w) + w1 * (b0.w + b1.w);
    ((float4*)(out + (size_t)t * CDIM))[c4] = o;
}

// ---------------------------------------------------------------------------
extern "C" void kernel_launch(void* const* d_in, const int* in_sizes, int n_in,
                              void* d_out, int out_size, void* d_ws, size_t ws_size,
                              hipStream_t stream) {
    const float* x  = (const float*)d_in[0];
    const float* Wg = (const float*)d_in[1];
    const float* bg = (const float*)d_in[2];
    const float* W1 = (const float*)d_in[3];
    const float* b1 = (const float*)d_in[4];
    const float* W2 = (const float*)d_in[5];
    const float* b2 = (const float*)d_in[6];
    float* out = (float*)d_out;
    char* ws = (char*)d_ws;

    // workspace layout (bytes)
    size_t off = 0;
    int*    counts = (int*)(ws + off);    off += 256;
    int*    tlist  = (int*)(ws + off);    off += (size_t)NEXP * NTOK * 4;        // 128 KB
    float*  wslot  = (float*)(ws + off);  off += (size_t)NTOK * TOPK * 4;        // 32 KB
    ushort* xbf    = (ushort*)(ws + off); off += (size_t)NTOK * CDIM * 2;        // 8 MB
    ushort* WT     = (ushort*)(ws + off); off += (size_t)NEXP * CDIM * HDIM * 2; // 64 MB (shared W1T/W2T)
    ushort* h      = (ushort*)(ws + off); off += (size_t)NTOK * TOPK * HDIM * 2; // 64 MB
    float*  y      = (float*)(ws + off);  off += (size_t)NTOK * TOPK * CDIM * 4 * 2; // 64 MB (2 split-K partials)

    hipMemsetAsync(counts, 0, NEXP * sizeof(int), stream);

    gate_kernel<<<NTOK / 4, 256, 0, stream>>>(x, Wg, bg, counts, tlist, wslot, xbf);

    // W1 [E][C][H] -> WT [E][H][C] bf16
    transpose_kernel<<<dim3(HDIM / 64, CDIM / 64, NEXP), 256, 0, stream>>>(
        W1, WT, CDIM, HDIM);

    // h[slot] = gelu(x @ W1 + b1), bf16.  flat grid = 8 experts x 32 mt x 32 nj
    moe_gemm<1, 1><<<NEXP * 32 * (HDIM / 128), 256, 0, stream>>>(
        xbf, WT, b1, tlist, counts, (void*)h, CDIM, HDIM, 1,
        HDIM / 128 - 1, 5, CDIM, 0);

    // W2 [E][H][C] -> WT [E][C][H] bf16  (reuses WT buffer; stream-ordered
    // after GEMM1 so the overwrite is safe)
    transpose_kernel<<<dim3(CDIM / 64, HDIM / 64, NEXP), 256, 0, stream>>>(
        W2, WT, HDIM, CDIM);

    // y[split][slot] = h @ W2 (+ b2 on split 0), f32; split-K x2.
    // flat grid = 8 experts x 32 mt x (8 n-tiles * 2 splits)
    moe_gemm<0, 0><<<NEXP * 32 * (CDIM / 128) * 2, 256, 0, stream>>>(
        h, WT, b2, tlist, counts, (void*)y, HDIM, CDIM, 0,
        CDIM / 128 - 1, 3, HDIM / 2, (size_t)NTOK * TOPK * CDIM);

    combine_kernel<<<(NTOK * CDIM / 4) / 256, 256, 0, stream>>>(y, wslot, out);
}

// Round 4
// 656.837 us; speedup vs baseline: 1.0778x; 1.0466x over previous
//
#include <hip/hip_runtime.h>
#include <hip/hip_bf16.h>
#include <math.h>

// Problem constants
#define NTOK  4096      // B*T
#define CDIM  1024
#define HDIM  4096
#define NEXP  8
#define TOPK  2

using short8 = __attribute__((ext_vector_type(8))) short;
using f32x4  = __attribute__((ext_vector_type(4))) float;

__device__ inline ushort f2bf(float f) {
    uint32_t u = __builtin_bit_cast(uint32_t, f);
    uint32_t r = (u + 0x7FFFu + ((u >> 16) & 1u)) >> 16;
    return (ushort)r;
}

// gelu(v) = 0.5 v (1 + erf(v/sqrt2)); erf via Abramowitz-Stegun 7.1.26,
// |abs err| <= 1.5e-7 -- ~5000x below the bf16 rounding floor of h, so the
// output absmax is unchanged vs libm erff, at ~half the VALU ops.
__device__ __forceinline__ float gelu_fast(float v) {
    float z = fabsf(v) * 0.70710678118654752f;
    float t = 1.0f / fmaf(0.3275911f, z, 1.0f);
    float p = t * fmaf(t, fmaf(t, fmaf(t, fmaf(t, 1.061405429f, -1.453152027f),
                                        1.421413741f), -0.284496736f), 0.254829592f);
    float erfz = 1.0f - p * __expf(-z * z);
    return 0.5f * v * (1.0f + copysignf(erfz, v));
}

// async global->LDS, 16 B per lane; LDS dest = wave-uniform base + lane*16
__device__ __forceinline__ void gl_lds16(const void* g, void* l) {
    __builtin_amdgcn_global_load_lds(
        (const __attribute__((address_space(1))) void*)(void*)g,
        (__attribute__((address_space(3))) void*)l, 16, 0, 0);
}

#define SCHED_FENCE() __builtin_amdgcn_sched_barrier(0)
#define RAW_BAR()  { SCHED_FENCE(); __builtin_amdgcn_s_barrier(); SCHED_FENCE(); }

// ---------------------------------------------------------------------------
// Gate: one wave per token. fp32 logits, top-2, normalized weights.
// Also converts x to bf16.
__global__ __launch_bounds__(256)
void gate_kernel(const float* __restrict__ x, const float* __restrict__ Wg,
                 const float* __restrict__ bg, int* __restrict__ counts,
                 int* __restrict__ tlist, float* __restrict__ wslot,
                 ushort* __restrict__ xbf) {
    int wave = threadIdx.x >> 6, lane = threadIdx.x & 63;
    int t = blockIdx.x * 4 + wave;
    const float* xr = x + (size_t)t * CDIM;

    float acc[NEXP];
#pragma unroll
    for (int e = 0; e < NEXP; e++) acc[e] = 0.f;

#pragma unroll
    for (int i = 0; i < CDIM / 64; i++) {
        int c = lane + 64 * i;
        float xv = xr[c];
        xbf[(size_t)t * CDIM + c] = f2bf(xv);
        const float* wr = Wg + (size_t)c * NEXP;
#pragma unroll
        for (int e = 0; e < NEXP; e++) acc[e] += xv * wr[e];
    }
#pragma unroll
    for (int e = 0; e < NEXP; e++) {
        float v = acc[e];
        for (int off = 32; off > 0; off >>= 1) v += __shfl_xor(v, off);
        acc[e] = v + bg[e];
    }
    if (lane == 0) {
        int i1 = 0; float m1 = acc[0];
#pragma unroll
        for (int e = 1; e < NEXP; e++) if (acc[e] > m1) { m1 = acc[e]; i1 = e; }
        int i2 = -1; float m2 = -1e30f;
#pragma unroll
        for (int e = 0; e < NEXP; e++) if (e != i1 && acc[e] > m2) { m2 = acc[e]; i2 = e; }
        // softmax top-2 renormalized: w0 = g1/(g1+g2) = 1/(1+exp(l2-l1))
        float w0 = 1.f / (1.f + expf(m2 - m1));
        float w1 = 1.f - w0;
        int p0 = atomicAdd(&counts[i1], 1);
        tlist[i1 * NTOK + p0] = t * 2;
        int p1 = atomicAdd(&counts[i2], 1);
        tlist[i2 * NTOK + p1] = t * 2 + 1;
        wslot[t * 2]     = w0;
        wslot[t * 2 + 1] = w1;
    }
}

// ---------------------------------------------------------------------------
// Transpose + fp32->bf16: in [E][R][Ccols] f32 -> out [E][Ccols][R] bf16
// 64x64 tiles, 256 threads. Vector LDS ops, XOR-swizzled bf16 tile (both
// sides <=2-way), 16B loads and stores. grid (Ccols/64, R/64, E)
__global__ __launch_bounds__(256)
void transpose_kernel(const float* __restrict__ in, ushort* __restrict__ out,
                      int R, int Ccols) {
    __shared__ ushort tile[64 * 64];   // 8 KB, swizzled addressing below
    int e = blockIdx.z;
    const float* src = in + (size_t)e * R * Ccols;
    ushort* dst = out + (size_t)e * Ccols * R;
    int c0 = blockIdx.x * 64, r0 = blockIdx.y * 64;
    int tid = threadIdx.x;
    int tx = tid & 15, ty = tid >> 4;

    float4 v[4];
#pragma unroll
    for (int j = 0; j < 4; j++)
        v[j] = *(const float4*)&src[(size_t)(r0 + ty * 4 + j) * Ccols + c0 + tx * 4];

    // element (c, r) lives at byte  c*128 + (((r>>3) ^ ((c>>2)&7))<<4) + (r&7)*2
#pragma unroll
    for (int i = 0; i < 4; i++) {
        int c = tx * 4 + i;
        uint2 pr;
        pr.x = (uint)f2bf(v[0][i]) | ((uint)f2bf(v[1][i]) << 16);
        pr.y = (uint)f2bf(v[2][i]) | ((uint)f2bf(v[3][i]) << 16);
        int gr = (ty >> 1) ^ ((c >> 2) & 7);            // r = 4*ty -> r>>3 = ty>>1
        int off = c * 128 + (gr << 4) + (ty & 1) * 8;   // bytes; 8-aligned
        *(uint2*)((char*)tile + off) = pr;
    }
    __syncthreads();

#pragma unroll
    for (int p = 0; p < 2; p++) {
        int c   = (tid >> 3) + 32 * p;                  // dst row within tile
        int rch = tid & 7;                              // r granule (8 elems)
        int gr  = rch ^ ((c >> 2) & 7);
        short8 val = *(short8*)((char*)tile + c * 128 + (gr << 4));
        *(short8*)&dst[(size_t)(c0 + c) * R + r0 + rch * 8] = val;
    }
}

// ---------------------------------------------------------------------------
// Sparse-expert GEMM: rows gathered by per-expert token list.
//   A  : bf16 [*, K], row index = tlist_value >> ashift
//   Bt : bf16 [E][N][K] (pre-transposed so rows are K-consecutive)
//   Out: row index = tlist_value; bf16 (h) or f32 (y)
// 128x128 tile, BK=32, 4 waves x (64x64), v_mfma_f32_16x16x32_bf16.
//
// 1-D grid, expert->XCD partition (bijective decode; G16-safe).
// Split-K (GEMM2 only): separate partial buffers, no atomics.
//
// T4 counted-vmcnt pipeline: raw s_barrier + s_waitcnt vmcnt(4) instead of
// __syncthreads (which drains vmcnt(0) and eats the whole load latency every
// K-step -- the measured MfmaUtil-19% stall). Invariant: each wave has
// exactly {cur 4, next 4} gl_lds in flight; vmcnt(4) retires the cur buffer,
// whose loads were issued one full compute phase + two barriers earlier.
// Safety: identical 2-barrier structure as before (barrier-1 = cur staged by
// ALL waves since each executed its own vmcnt(4); barrier-2 = cur reads
// consumed by MFMAs before overwrite). sched_barrier(0) at every wait fences
// compiler motion across the asm (rule 18); no other vmem ops are emitted
// inside the loop, so the counts stay exact.
template<int GELU, int OUTBF16>
__global__ __launch_bounds__(256, 3)
void moe_gemm(const ushort* __restrict__ A, const ushort* __restrict__ Bt,
              const float* __restrict__ bias, const int* __restrict__ tlist,
              const int* __restrict__ counts, void* __restrict__ Out,
              int K, int N, int ashift, int nxmask, int nxshift, int ksplit,
              size_t psz) {
    int flat = blockIdx.x;
    int e  = flat & 7;
    int j  = flat >> 3;
    int mt = j & 31;              // m-tile innermost within an XCD
    int nj = j >> 5;
    int cnt = counts[e];
    int m0 = mt * 128;
    if (m0 >= cnt) return;
    int n0 = (nj & nxmask) * 128;
    int split = nj >> nxshift;
    int kbeg = split * ksplit;

    __shared__ ushort As[2][128 * 32];
    __shared__ ushort Bs[2][128 * 32];
    __shared__ int rowv[128];

    int tid = threadIdx.x;
    if (tid < 128) {
        int r = m0 + tid;
        rowv[tid] = tlist[e * NTOK + (r < cnt ? r : cnt - 1)];
    }
    __syncthreads();              // full drain: vmcnt baseline 0 for the loop

    const ushort* Be = Bt + (size_t)e * N * K;

    int lane = tid & 63, w = tid >> 6;
    int wm = (w >> 1) * 64, wn = (w & 1) * 64;
    int quad = lane >> 4, l16 = lane & 15;

    // Staging: thread covers rows srow and srow+64, one 16 B chunk each.
    // Source chunk is pre-swizzled; LDS dest stays linear (base + lane*16).
    int srow   = tid >> 2;
    int schunk = (tid & 3) ^ ((tid >> 3) & 3);   // == q ^ ((srow>>1)&3)
    const ushort* pa0 = A  + (size_t)(rowv[srow]      >> ashift) * K + kbeg + schunk * 8;
    const ushort* pa1 = A  + (size_t)(rowv[srow + 64] >> ashift) * K + kbeg + schunk * 8;
    const ushort* pb0 = Be + (size_t)(n0 + srow)      * K + kbeg + schunk * 8;
    const ushort* pb1 = Be + (size_t)(n0 + srow + 64) * K + kbeg + schunk * 8;

    // Fragment-read swizzle: phys chunk = quad ^ ((row>>1)&3); the row's
    // high bits (wm/wn + mt*16) contribute 0 mod 4, so it's quad ^ ((l16>>1)&3).
    int swr  = quad ^ ((l16 >> 1) & 3);
    int aidx = (wm + l16) * 32 + swr * 8;
    int bidx = (wn + l16) * 32 + swr * 8;

    f32x4 acc[4][4] = {};

    auto STAGE = [&](int buf) {
        gl_lds16(pa0, &As[buf][(w * 16) * 32]);
        gl_lds16(pa1, &As[buf][(w * 16 + 64) * 32]);
        gl_lds16(pb0, &Bs[buf][(w * 16) * 32]);
        gl_lds16(pb1, &Bs[buf][(w * 16 + 64) * 32]);
        pa0 += 32; pa1 += 32; pb0 += 32; pb1 += 32;
    };
    auto COMPUTE = [&](int buf) {
        short8 a[4], b[4];
#pragma unroll
        for (int mti = 0; mti < 4; mti++) a[mti] = *(short8*)&As[buf][aidx + mti * 512];
#pragma unroll
        for (int nti = 0; nti < 4; nti++) b[nti] = *(short8*)&Bs[buf][bidx + nti * 512];
#pragma unroll
        for (int mti = 0; mti < 4; mti++)
#pragma unroll
            for (int nti = 0; nti < 4; nti++)
                acc[mti][nti] = __builtin_amdgcn_mfma_f32_16x16x32_bf16(
                    a[mti], b[nti], acc[mti][nti], 0, 0, 0);
    };

    int nsteps = ksplit >> 5;     // 32 (GEMM1) or 64 (GEMM2 split)
    STAGE(0);                     // 4 outstanding
    for (int i = 0; i < nsteps - 1; ++i) {
        int b = i & 1;
        STAGE(1 - b);             // +4 -> 8 outstanding
        asm volatile("s_waitcnt vmcnt(4)" ::: "memory");   // cur's 4 done
        RAW_BAR();                // all waves' cur writes landed
        COMPUTE(b);               // ds_read + MFMA (compiler inserts lgkmcnt)
        RAW_BAR();                // cur reads consumed -> next iter may overwrite
    }
    asm volatile("s_waitcnt vmcnt(0)" ::: "memory");
    RAW_BAR();
    COMPUTE((nsteps - 1) & 1);

    // Epilogue. C/D layout: col = lane&15, row = (lane>>4)*4 + reg.
    float* outF = (float*)Out + split * psz;
    ushort* outH = (ushort*)Out;
    const float* be = bias + (size_t)e * N;
    float bv[4];
#pragma unroll
    for (int nti = 0; nti < 4; nti++)
        bv[nti] = (split == 0) ? be[n0 + wn + nti * 16 + l16] : 0.f;
#pragma unroll
    for (int mti = 0; mti < 4; mti++) {
#pragma unroll
        for (int r = 0; r < 4; r++) {
            int lrow = wm + mti * 16 + quad * 4 + r;
            if (m0 + lrow < cnt) {
                int v = rowv[lrow];
                size_t base = (size_t)v * N;
#pragma unroll
                for (int nti = 0; nti < 4; nti++) {
                    int col = n0 + wn + nti * 16 + l16;
                    float val = acc[mti][nti][r] + bv[nti];
                    if (GELU) val = gelu_fast(val);
                    if (OUTBF16) outH[base + col] = f2bf(val);
                    else         outF[base + col] = val;
                }
            }
        }
    }
}

// ---------------------------------------------------------------------------
// out[t] = w0 * (ya[2t]+yb[2t]) + w1 * (ya[2t+1]+yb[2t+1])
// (split-K partial sum folded in; fully coalesced)
__global__ __launch_bounds__(256)
void combine_kernel(const float* __restrict__ y, const float* __restrict__ wslot,
                    float* __restrict__ out) {
    const float* y2 = y + (size_t)NTOK * TOPK * CDIM;   // split-1 partials
    int idx = blockIdx.x * 256 + threadIdx.x;     // one float4 each
    int c4 = idx & (CDIM / 4 - 1);
    int t = idx >> 8;                              // CDIM/4 == 256
    float w0 = wslot[2 * t], w1 = wslot[2 * t + 1];
    const float4* y0a = (const float4*)(y  + (size_t)(2 * t) * CDIM);
    const float4* y1a = (const float4*)(y  + (size_t)(2 * t + 1) * CDIM);
    const float4* y0b = (const float4*)(y2 + (size_t)(2 * t) * CDIM);
    const float4* y1b = (const float4*)(y2 + (size_t)(2 * t + 1) * CDIM);
    float4 a0 = y0a[c4], a1 = y0b[c4], b0 = y1a[c4], b1 = y1b[c4], o;
    o.x = w0 * (a0.x + a1.x) + w1 * (b0.x + b1.x);
    o.y = w0 * (a0.y + a1.y) + w1 * (b0.y + b1.y);
    o.z = w0 * (a0.z + a1.z) + w1 * (b0.z + b1.z);
    o.w = w0 * (a0.w + a1.w) + w1 * (b0.w + b1.w);
    ((float4*)(out + (size_t)t * CDIM))[c4] = o;
}

// ---------------------------------------------------------------------------
extern "C" void kernel_launch(void* const* d_in, const int* in_sizes, int n_in,
                              void* d_out, int out_size, void* d_ws, size_t ws_size,
                              hipStream_t stream) {
    const float* x  = (const float*)d_in[0];
    const float* Wg = (const float*)d_in[1];
    const float* bg = (const float*)d_in[2];
    const float* W1 = (const float*)d_in[3];
    const float* b1 = (const float*)d_in[4];
    const float* W2 = (const float*)d_in[5];
    const float* b2 = (const float*)d_in[6];
    float* out = (float*)d_out;
    char* ws = (char*)d_ws;

    // workspace layout (bytes)
    size_t off = 0;
    int*    counts = (int*)(ws + off);    off += 256;
    int*    tlist  = (int*)(ws + off);    off += (size_t)NEXP * NTOK * 4;        // 128 KB
    float*  wslot  = (float*)(ws + off);  off += (size_t)NTOK * TOPK * 4;        // 32 KB
    ushort* xbf    = (ushort*)(ws + off); off += (size_t)NTOK * CDIM * 2;        // 8 MB
    ushort* WT     = (ushort*)(ws + off); off += (size_t)NEXP * CDIM * HDIM * 2; // 64 MB (shared W1T/W2T)
    ushort* h      = (ushort*)(ws + off); off += (size_t)NTOK * TOPK * HDIM * 2; // 64 MB
    float*  y      = (float*)(ws + off);  off += (size_t)NTOK * TOPK * CDIM * 4 * 2; // 64 MB (2 split-K partials)

    hipMemsetAsync(counts, 0, NEXP * sizeof(int), stream);

    gate_kernel<<<NTOK / 4, 256, 0, stream>>>(x, Wg, bg, counts, tlist, wslot, xbf);

    // W1 [E][C][H] -> WT [E][H][C] bf16
    transpose_kernel<<<dim3(HDIM / 64, CDIM / 64, NEXP), 256, 0, stream>>>(
        W1, WT, CDIM, HDIM);

    // h[slot] = gelu(x @ W1 + b1), bf16.  flat grid = 8 experts x 32 mt x 32 nj
    moe_gemm<1, 1><<<NEXP * 32 * (HDIM / 128), 256, 0, stream>>>(
        xbf, WT, b1, tlist, counts, (void*)h, CDIM, HDIM, 1,
        HDIM / 128 - 1, 5, CDIM, 0);

    // W2 [E][H][C] -> WT [E][C][H] bf16  (reuses WT buffer; stream-ordered
    // after GEMM1 so the overwrite is safe)
    transpose_kernel<<<dim3(CDIM / 64, HDIM / 64, NEXP), 256, 0, stream>>>(
        W2, WT, HDIM, CDIM);

    // y[split][slot] = h @ W2 (+ b2 on split 0), f32; split-K x2.
    // flat grid = 8 experts x 32 mt x (8 n-tiles * 2 splits)
    moe_gemm<0, 0><<<NEXP * 32 * (CDIM / 128) * 2, 256, 0, stream>>>(
        h, WT, b2, tlist, counts, (void*)y, HDIM, CDIM, 0,
        CDIM / 128 - 1, 3, HDIM / 2, (size_t)NTOK * TOPK * CDIM);

    combine_kernel<<<(NTOK * CDIM / 4) / 256, 256, 0, stream>>>(y, wslot, out);
}